// Round 1
// 412.935 us; speedup vs baseline: 1.0093x; 1.0093x over previous
//
#include <hip/hip_runtime.h>
#include <hip/hip_bf16.h>
#include <math.h>

#define DIMC 512
#define NPT  4096
#define BATCH 16
#define KSPLIT 4

typedef __bf16 bf16x4 __attribute__((ext_vector_type(4)));
typedef __bf16 bf16x8 __attribute__((ext_vector_type(8)));
typedef float  f32x4  __attribute__((ext_vector_type(4)));

typedef const __attribute__((address_space(1))) unsigned int guint;
typedef __attribute__((address_space(3))) unsigned int luint;

__device__ inline void gl_lds16(const void* g, void* l) {
  __builtin_amdgcn_global_load_lds((guint*)g, (luint*)l, 16, 0, 0);
}

__device__ inline unsigned short bfbits(float f) {
  union { __bf16 h; unsigned short u; } cv;
  cv.h = (__bf16)f;
  return cv.u;
}

// ---------------------------------------------------------------------------
// Gram, upper-triangle 128-tiles only, split-K x4, XCD-swizzled 1D grid.
// ---------------------------------------------------------------------------
__global__ __launch_bounds__(256, 4) void gram_split(
    const __bf16* __restrict__ xb, float* __restrict__ Gp)
{
  static const int TI[10] = {0,0,0,0,1,1,1,2,2,3};
  static const int TJ[10] = {0,1,2,3,1,2,3,2,3,3};
  const int id = blockIdx.x;              // 640 = 8 XCD * 8 pair-groups * 10 tiles
  const int xcd = id & 7, slot = id >> 3;
  const int g = slot / 10, t = slot % 10;
  const int pair = xcd + 8 * g;
  const int b = pair >> 2, s = pair & 3;
  const int m0 = TI[t] * 128, n0 = TJ[t] * 128;

  const __bf16* A = xb + (long)b * DIMC * NPT;
  float* C = Gp + (long)pair * DIMC * DIMC;

  __shared__ alignas(16) __bf16 As[128 * 32];
  __shared__ alignas(16) __bf16 Bs[128 * 32];

  const int tid  = threadIdx.x;
  const int wave = tid >> 6, lane = tid & 63;
  const int wr = wave >> 1, wc = wave & 1;
  const int q = lane >> 4, p = lane & 15;
  const int r4 = lane >> 2;
  const int koff = (lane & 3) * 8;

  f32x4 acc[4][4];
#pragma unroll
  for (int i = 0; i < 4; ++i)
#pragma unroll
    for (int j = 0; j < 4; ++j) acc[i][j] = (f32x4){0.f, 0.f, 0.f, 0.f};

  const __bf16* gA = A + (long)m0 * NPT;
  const __bf16* gB = A + (long)n0 * NPT;
  const int kbeg = s * (NPT / KSPLIT), kend = kbeg + NPT / KSPLIT;

  for (int k0 = kbeg; k0 < kend; k0 += 32) {
    __syncthreads();
#pragma unroll
    for (int h = 0; h < 2; ++h) {
      const int chunk = wave + h * 4;
      gl_lds16(gA + (long)(chunk * 16 + r4) * NPT + k0 + koff, &As[chunk * 512]);
      gl_lds16(gB + (long)(chunk * 16 + r4) * NPT + k0 + koff, &Bs[chunk * 512]);
    }
    __syncthreads();

    bf16x8 af[4], bfv[4];
#pragma unroll
    for (int i = 0; i < 4; ++i)
      af[i] = ((const bf16x8*)As)[(wr * 64 + i * 16 + p) * 4 + q];
#pragma unroll
    for (int j = 0; j < 4; ++j)
      bfv[j] = ((const bf16x8*)Bs)[(wc * 64 + j * 16 + p) * 4 + q];
#pragma unroll
    for (int i = 0; i < 4; ++i)
#pragma unroll
      for (int j = 0; j < 4; ++j)
        acc[i][j] = __builtin_amdgcn_mfma_f32_16x16x32_bf16(af[i], bfv[j], acc[i][j], 0, 0, 0);
  }

#pragma unroll
  for (int i = 0; i < 4; ++i) {
    const int row = m0 + wr * 64 + i * 16 + q * 4;
#pragma unroll
    for (int j = 0; j < 4; ++j) {
      const int col = n0 + wc * 64 + j * 16 + p;
#pragma unroll
      for (int r = 0; r < 4; ++r)
        C[(long)(row + r) * DIMC + col] = acc[i][j][r];
    }
  }
}

// ---------------------------------------------------------------------------
// Reduce split-K partials of upper 64-tiles, emit Gh/Gl hi/lo, mirror lower.
// ---------------------------------------------------------------------------
__global__ __launch_bounds__(256) void gram_reduce_mirror(
    const float* __restrict__ Gp, __bf16* __restrict__ Gh, __bf16* __restrict__ Gl)
{
  const int bid = blockIdx.x;
  const int b = bid / 36;
  int rem = bid % 36, I = 0;
  while (rem >= 8 - I) { rem -= 8 - I; ++I; }
  const int J = I + rem;

  __shared__ float T[64][65];
  const int tid = threadIdx.x;
  const int r = tid >> 2, c0 = (tid & 3) * 16;

  float v[16];
#pragma unroll
  for (int e = 0; e < 16; ++e) v[e] = 0.f;
#pragma unroll
  for (int s = 0; s < KSPLIT; ++s) {
    const float* src = Gp + (long)(b * KSPLIT + s) * DIMC * DIMC
                          + (long)(I * 64 + r) * DIMC + J * 64 + c0;
#pragma unroll
    for (int q = 0; q < 4; ++q) {
      float4 t4 = ((const float4*)src)[q];
      v[q * 4 + 0] += t4.x; v[q * 4 + 1] += t4.y;
      v[q * 4 + 2] += t4.z; v[q * 4 + 3] += t4.w;
    }
  }

  const long gbase = (long)b * DIMC * DIMC;
#pragma unroll
  for (int q = 0; q < 4; ++q) {
    bf16x4 h, l;
#pragma unroll
    for (int e = 0; e < 4; ++e) {
      float f = v[q * 4 + e];
      __bf16 hh = (__bf16)f;
      h[e] = hh; l[e] = (__bf16)(f - (float)hh);
    }
    const long o = gbase + (long)(I * 64 + r) * DIMC + J * 64 + c0 + q * 4;
    *(bf16x4*)(Gh + o) = h;
    *(bf16x4*)(Gl + o) = l;
  }
#pragma unroll
  for (int e = 0; e < 16; ++e) T[r][c0 + e] = v[e];
  __syncthreads();
  if (I != J) {
#pragma unroll
    for (int q = 0; q < 4; ++q) {
      bf16x4 h, l;
#pragma unroll
      for (int e = 0; e < 4; ++e) {
        float f = T[c0 + q * 4 + e][r];
        __bf16 hh = (__bf16)f;
        h[e] = hh; l[e] = (__bf16)(f - (float)hh);
      }
      const long o = gbase + (long)(J * 64 + r) * DIMC + I * 64 + c0 + q * 4;
      *(bf16x4*)(Gh + o) = h;
      *(bf16x4*)(Gl + o) = l;
    }
  }
}

// ---------------------------------------------------------------------------
// 3-term hi/lo NT GEMM, 64M x 128N tile, BK=32, 4 waves (2x2, each 32x64).
// 6 gl_lds + 24 MFMA per K-iter. Grid (N/128, M/64, BATCH) = 512 blocks.
// ---------------------------------------------------------------------------
template <bool SPLIT_OUT>
__global__ __launch_bounds__(256, 4) void gemm3_nt(
    const __bf16* __restrict__ Ah, const __bf16* __restrict__ Al,
    const __bf16* __restrict__ Bh, const __bf16* __restrict__ Bl,
    float* __restrict__ Cf, __bf16* __restrict__ Ch, __bf16* __restrict__ Cl,
    int K, long sA, long sB, long sC, float alpha)
{
  const int b = blockIdx.z;
  Ah += (long)b * sA;  Al += (long)b * sA;
  Bh += (long)b * sB;  Bl += (long)b * sB;
  const int m0 = blockIdx.y * 64, n0 = blockIdx.x * 128;

  __shared__ alignas(16) __bf16 sAh[64 * 32],  sAl[64 * 32];
  __shared__ alignas(16) __bf16 sBh[128 * 32], sBl[128 * 32];

  const int tid  = threadIdx.x;
  const int wave = tid >> 6, lane = tid & 63;
  const int wr = wave >> 1, wc = wave & 1;
  const int q = lane >> 4, p = lane & 15;
  const int r4 = lane >> 2;
  const int koff = (lane & 3) * 8;

  f32x4 acc[2][4];
#pragma unroll
  for (int i = 0; i < 2; ++i)
#pragma unroll
    for (int j = 0; j < 4; ++j) acc[i][j] = (f32x4){0.f, 0.f, 0.f, 0.f};

  const long arow = (long)(m0 + wave * 16 + r4) * K + koff;

  for (int k0 = 0; k0 < K; k0 += 32) {
    __syncthreads();
    gl_lds16(Ah + arow + k0, &sAh[wave * 512]);
    gl_lds16(Al + arow + k0, &sAl[wave * 512]);
#pragma unroll
    for (int h = 0; h < 2; ++h) {
      const int chunk = wave + h * 4;
      const long brow = (long)(n0 + chunk * 16 + r4) * K + koff + k0;
      gl_lds16(Bh + brow, &sBh[chunk * 512]);
      gl_lds16(Bl + brow, &sBl[chunk * 512]);
    }
    __syncthreads();

    bf16x8 fah[2], fal[2], fbh[4], fbl[4];
#pragma unroll
    for (int i = 0; i < 2; ++i) {
      const int idx = (wr * 32 + i * 16 + p) * 4 + q;
      fah[i] = ((const bf16x8*)sAh)[idx];
      fal[i] = ((const bf16x8*)sAl)[idx];
    }
#pragma unroll
    for (int j = 0; j < 4; ++j) {
      const int idx = (wc * 64 + j * 16 + p) * 4 + q;
      fbh[j] = ((const bf16x8*)sBh)[idx];
      fbl[j] = ((const bf16x8*)sBl)[idx];
    }
#pragma unroll
    for (int i = 0; i < 2; ++i)
#pragma unroll
      for (int j = 0; j < 4; ++j) {
        acc[i][j] = __builtin_amdgcn_mfma_f32_16x16x32_bf16(fah[i], fbh[j], acc[i][j], 0, 0, 0);
        acc[i][j] = __builtin_amdgcn_mfma_f32_16x16x32_bf16(fah[i], fbl[j], acc[i][j], 0, 0, 0);
        acc[i][j] = __builtin_amdgcn_mfma_f32_16x16x32_bf16(fal[i], fbh[j], acc[i][j], 0, 0, 0);
      }
  }

#pragma unroll
  for (int i = 0; i < 2; ++i) {
    const int row = m0 + wr * 32 + i * 16 + q * 4;
#pragma unroll
    for (int j = 0; j < 4; ++j) {
      const int col = n0 + wc * 64 + j * 16 + p;
#pragma unroll
      for (int r = 0; r < 4; ++r) {
        const float f = acc[i][j][r] * alpha;
        const long o = (long)b * sC + (long)(row + r) * DIMC + col;
        if (SPLIT_OUT) {
          __bf16 hh = (__bf16)f;
          Ch[o] = hh;
          Cl[o] = (__bf16)(f - (float)hh);
        } else {
          Cf[o] = f;
        }
      }
    }
  }
}

// ---------------------------------------------------------------------------
// Single-term NT GEMM bf16, 64M x 128N tile (M = P . Wv^T). 3 gl_lds + 8 MFMA.
// ---------------------------------------------------------------------------
__global__ __launch_bounds__(256, 4) void gemm_nt64x128(
    const __bf16* __restrict__ A, const __bf16* __restrict__ B,
    __bf16* __restrict__ C, int K, long sA, long sB, long sC)
{
  const int b = blockIdx.z;
  A += (long)b * sA;  B += (long)b * sB;  C += (long)b * sC;
  const int m0 = blockIdx.y * 64, n0 = blockIdx.x * 128;

  __shared__ alignas(16) __bf16 As[64 * 32];
  __shared__ alignas(16) __bf16 Bs[128 * 32];

  const int tid  = threadIdx.x;
  const int wave = tid >> 6, lane = tid & 63;
  const int wr = wave >> 1, wc = wave & 1;
  const int q = lane >> 4, p = lane & 15;
  const int r4 = lane >> 2;
  const int koff = (lane & 3) * 8;

  f32x4 acc[2][4];
#pragma unroll
  for (int i = 0; i < 2; ++i)
#pragma unroll
    for (int j = 0; j < 4; ++j) acc[i][j] = (f32x4){0.f, 0.f, 0.f, 0.f};

  const long arow = (long)(m0 + wave * 16 + r4) * K + koff;

  for (int k0 = 0; k0 < K; k0 += 32) {
    __syncthreads();
    gl_lds16(A + arow + k0, &As[wave * 512]);
#pragma unroll
    for (int h = 0; h < 2; ++h) {
      const int chunk = wave + h * 4;
      gl_lds16(B + (long)(n0 + chunk * 16 + r4) * K + koff + k0, &Bs[chunk * 512]);
    }
    __syncthreads();

    bf16x8 af[2], bfv[4];
#pragma unroll
    for (int i = 0; i < 2; ++i)
      af[i] = ((const bf16x8*)As)[(wr * 32 + i * 16 + p) * 4 + q];
#pragma unroll
    for (int j = 0; j < 4; ++j)
      bfv[j] = ((const bf16x8*)Bs)[(wc * 64 + j * 16 + p) * 4 + q];
#pragma unroll
    for (int i = 0; i < 2; ++i)
#pragma unroll
      for (int j = 0; j < 4; ++j)
        acc[i][j] = __builtin_amdgcn_mfma_f32_16x16x32_bf16(af[i], bfv[j], acc[i][j], 0, 0, 0);
  }

#pragma unroll
  for (int i = 0; i < 2; ++i) {
    const int row = m0 + wr * 32 + i * 16 + q * 4;
#pragma unroll
    for (int j = 0; j < 4; ++j) {
      const int col = n0 + wc * 64 + j * 16 + p;
#pragma unroll
      for (int r = 0; r < 4; ++r)
        C[(long)(row + r) * DIMC + col] = (__bf16)acc[i][j][r];
    }
  }
}

// ---------------------------------------------------------------------------
// Final GEMM: out_b[d,n] = sum_c Mm_b[d,c] xt_b[n,c]. 128x128, XCD swizzle.
// ---------------------------------------------------------------------------
__global__ __launch_bounds__(256, 2) void gemm_final(
    const __bf16* __restrict__ Mm, const __bf16* __restrict__ xt,
    float* __restrict__ out)
{
  const int id = blockIdx.x;
  const int xcd = id & 7, slot = id >> 3;
  const int g = slot >> 7, tile = slot & 127;
  const int b = xcd + 8 * g;
  const int m0 = (tile >> 5) * 128, n0 = (tile & 31) * 128;

  const __bf16* A = Mm + (long)b * DIMC * DIMC;
  const __bf16* B = xt + (long)b * NPT * DIMC;
  float* C = out + (long)b * DIMC * NPT;
  const int K = DIMC;

  __shared__ alignas(16) __bf16 As[128 * 32];
  __shared__ alignas(16) __bf16 Bs[128 * 32];

  const int tid  = threadIdx.x;
  const int wave = tid >> 6, lane = tid & 63;
  const int wr = wave >> 1, wc = wave & 1;
  const int q = lane >> 4, p = lane & 15;
  const int r4 = lane >> 2;
  const int koff = (lane & 3) * 8;

  f32x4 acc[4][4];
#pragma unroll
  for (int i = 0; i < 4; ++i)
#pragma unroll
    for (int j = 0; j < 4; ++j) acc[i][j] = (f32x4){0.f, 0.f, 0.f, 0.f};

  const __bf16* gA = A + (long)m0 * K;
  const __bf16* gB = B + (long)n0 * K;

  for (int k0 = 0; k0 < K; k0 += 32) {
    __syncthreads();
#pragma unroll
    for (int h = 0; h < 2; ++h) {
      const int chunk = wave + h * 4;
      gl_lds16(gA + (long)(chunk * 16 + r4) * K + k0 + koff, &As[chunk * 512]);
      gl_lds16(gB + (long)(chunk * 16 + r4) * K + k0 + koff, &Bs[chunk * 512]);
    }
    __syncthreads();

    bf16x8 af[4], bfv[4];
#pragma unroll
    for (int i = 0; i < 4; ++i)
      af[i] = ((const bf16x8*)As)[(wr * 64 + i * 16 + p) * 4 + q];
#pragma unroll
    for (int j = 0; j < 4; ++j)
      bfv[j] = ((const bf16x8*)Bs)[(wc * 64 + j * 16 + p) * 4 + q];
#pragma unroll
    for (int i = 0; i < 4; ++i)
#pragma unroll
      for (int j = 0; j < 4; ++j)
        acc[i][j] = __builtin_amdgcn_mfma_f32_16x16x32_bf16(af[i], bfv[j], acc[i][j], 0, 0, 0);
  }

#pragma unroll
  for (int i = 0; i < 4; ++i) {
    const int row = m0 + wr * 64 + i * 16 + q * 4;
#pragma unroll
    for (int j = 0; j < 4; ++j) {
      const int col = n0 + wc * 64 + j * 16 + p;
#pragma unroll
      for (int r = 0; r < 4; ++r)
        C[(long)(row + r) * NPT + col] = acc[i][j][r];
    }
  }
}

// ---------------------------------------------------------------------------
// x [B,512,4096] fp32 -> xt [B,4096,512] bf16 AND xb [B,512,4096] bf16.
// Latency-oriented rewrite: 64c x 256n tile per block, 16 independent float4
// loads issued up-front per thread (4x the in-flight bytes of the old version),
// xb stores as before, LDS dword-pack via ds_write_b64 (4-way max), xt written
// as uint4 (16B/lane, 128B contiguous per 8-lane group). One barrier.
// ---------------------------------------------------------------------------
__global__ __launch_bounds__(256, 4) void transpose_convert_x(
    const float* __restrict__ x, __bf16* __restrict__ xt,
    __bf16* __restrict__ xb)
{
  const int b = blockIdx.z;
  const int n0 = blockIdx.x * 256, c0 = blockIdx.y * 64;
  const float* X = x + (long)b * DIMC * NPT;
  __bf16* XT = xt + (long)b * NPT * DIMC;
  __bf16* XB = xb + (long)b * DIMC * NPT;

  __shared__ unsigned int D[256 * 34];   // [n_local][c_pair], row stride 34 dwords

  const int t = threadIdx.x;
  const int w = t >> 6, lane = t & 63;
  const int rp = lane >> 4;              // row sub-group 0..3
  const int cg = lane & 15;              // n float4-group 0..15 within wave's 64n
  const int ncol = n0 + w * 64 + cg * 4; // global n of this thread's float4

  // 16 c-rows x 4 n-cols per thread; all 16 loads independent and in flight.
  f32x4 v[16];
#pragma unroll
  for (int i = 0; i < 4; ++i)
#pragma unroll
    for (int s = 0; s < 4; ++s)
      v[i * 4 + s] = *(const f32x4*)(X + (long)(c0 + i * 16 + rp * 4 + s) * NPT + ncol);

  // xb: bf16 copy of x (same layout). 128B contiguous per 16-lane group.
#pragma unroll
  for (int i = 0; i < 4; ++i)
#pragma unroll
    for (int s = 0; s < 4; ++s) {
      const f32x4 f = v[i * 4 + s];
      bf16x4 wv = {(__bf16)f[0], (__bf16)f[1], (__bf16)f[2], (__bf16)f[3]};
      *(bf16x4*)(XB + (long)(c0 + i * 16 + rp * 4 + s) * NPT + ncol) = wv;
    }

  // LDS dword-pack: D[nl][cp] = {bf16 x[c0+2cp][n], bf16 x[c0+2cp+1][n]}.
  // Per-instr banks: 8*(cg&3) + 2*rp + const -> 16 distinct, 4-way b64 writes.
#pragma unroll
  for (int i = 0; i < 4; ++i) {
    const int cp = i * 8 + rp * 2;
#pragma unroll
    for (int jj = 0; jj < 4; ++jj) {
      const int nl = w * 64 + cg * 4 + jj;
      const unsigned int d0 =
          ((unsigned int)bfbits(v[i * 4 + 1][jj]) << 16) | bfbits(v[i * 4 + 0][jj]);
      const unsigned int d1 =
          ((unsigned int)bfbits(v[i * 4 + 3][jj]) << 16) | bfbits(v[i * 4 + 2][jj]);
      uint2 u; u.x = d0; u.y = d1;
      *(uint2*)&D[nl * 34 + cp] = u;     // ds_write_b64 (8B aligned: even idx)
    }
  }
  __syncthreads();

  // xt: each thread stores 16B per row, 8 rows; 128B contiguous per 8 lanes.
  const int a = t & 7, nb = t >> 3;
#pragma unroll
  for (int pass = 0; pass < 8; ++pass) {
    const int n = pass * 32 + nb;
    const unsigned int* Dr = &D[n * 34 + a * 4];
    const uint2 lo = *(const uint2*)Dr;        // ds_read_b64 x2 (stride-34 rows
    const uint2 hi = *(const uint2*)(Dr + 2);  //  are not 16B aligned)
    uint4 o; o.x = lo.x; o.y = lo.y; o.z = hi.x; o.w = hi.y;
    *(uint4*)(XT + (long)(n0 + n) * DIMC + c0 + a * 8) = o;
  }
}

// ---------------------------------------------------------------------------
// Row softmax over 512 cols, fp32 in -> bf16 out. One wave per row.
// ---------------------------------------------------------------------------
__global__ __launch_bounds__(256) void softmax_rows(
    const float* __restrict__ S, __bf16* __restrict__ P)
{
  const int row = blockIdx.x * 4 + (threadIdx.x >> 6);
  const int lane = threadIdx.x & 63;
  const float4* s4 = (const float4*)(S + (long)row * DIMC);
  float4 a = s4[lane * 2], b = s4[lane * 2 + 1];
  float v[8] = {a.x, a.y, a.z, a.w, b.x, b.y, b.z, b.w};
  float m = v[0];
#pragma unroll
  for (int i = 1; i < 8; ++i) m = fmaxf(m, v[i]);
#pragma unroll
  for (int off = 32; off > 0; off >>= 1) m = fmaxf(m, __shfl_xor(m, off));
  float e[8], sum = 0.f;
#pragma unroll
  for (int i = 0; i < 8; ++i) { e[i] = expf(v[i] - m); sum += e[i]; }
#pragma unroll
  for (int off = 32; off > 0; off >>= 1) sum += __shfl_xor(sum, off);
  const float inv = 1.0f / sum;
  bf16x8 o;
#pragma unroll
  for (int i = 0; i < 8; ++i) o[i] = (__bf16)(e[i] * inv);
  ((bf16x8*)(P + (long)row * DIMC))[lane] = o;
}

// ---------------------------------------------------------------------------
// Split Wq, Wk into bf16 hi/lo; WvT[c,e] = bf16(Wv[e,c]).
// ---------------------------------------------------------------------------
__global__ __launch_bounds__(256) void make_w(
    const float* __restrict__ Wq, const float* __restrict__ Wk,
    const float* __restrict__ Wv,
    __bf16* __restrict__ Wqh, __bf16* __restrict__ Wql,
    __bf16* __restrict__ Wkh, __bf16* __restrict__ Wkl,
    __bf16* __restrict__ WvT)
{
  const int i = blockIdx.x * 256 + threadIdx.x;
  float q = Wq[i];
  __bf16 qh = (__bf16)q; Wqh[i] = qh; Wql[i] = (__bf16)(q - (float)qh);
  float k = Wk[i];
  __bf16 kh = (__bf16)k; Wkh[i] = kh; Wkl[i] = (__bf16)(k - (float)kh);
  const int e = i >> 9, c = i & 511;
  WvT[(long)c * DIMC + e] = (__bf16)Wv[i];
}

extern "C" void kernel_launch(void* const* d_in, const int* in_sizes, int n_in,
                              void* d_out, int out_size, void* d_ws, size_t ws_size,
                              hipStream_t stream)
{
  const float* x  = (const float*)d_in[0];
  const float* Wq = (const float*)d_in[1];
  const float* Wk = (const float*)d_in[2];
  const float* Wv = (const float*)d_in[3];
  float* out = (float*)d_out;

  char* ws = (char*)d_ws;
  size_t off = 0;
  auto alloc = [&](size_t bytes) -> void* {
    void* p = ws + off;
    off += (bytes + 255) & ~(size_t)255;
    return p;
  };
  const long s2 = (long)DIMC * DIMC;

  __bf16* xt  = (__bf16*)alloc((size_t)BATCH * NPT * DIMC * 2);
  __bf16* xb  = (__bf16*)alloc((size_t)BATCH * DIMC * NPT * 2);
  float*  Gp  = (float*) alloc((size_t)KSPLIT * BATCH * s2 * 4);
  __bf16* Gh  = (__bf16*)alloc((size_t)BATCH * s2 * 2);
  __bf16* Gl  = (__bf16*)alloc((size_t)BATCH * s2 * 2);
  __bf16* Hh  = (__bf16*)alloc((size_t)BATCH * s2 * 2);
  __bf16* Hl  = (__bf16*)alloc((size_t)BATCH * s2 * 2);
  __bf16* Wqh = (__bf16*)alloc((size_t)s2 * 2);
  __bf16* Wql = (__bf16*)alloc((size_t)s2 * 2);
  __bf16* Wkh = (__bf16*)alloc((size_t)s2 * 2);
  __bf16* Wkl = (__bf16*)alloc((size_t)s2 * 2);
  __bf16* WvT = (__bf16*)alloc((size_t)s2 * 2);
  float*  S  = (float*)Gp;    // alias: Gp dead after reduce
  __bf16* P  = Gl;            // alias: Gl dead after H-GEMM
  __bf16* Mm = Gh;            // alias: Gh dead after H-GEMM

  make_w<<<DIMC * DIMC / 256, 256, 0, stream>>>(Wq, Wk, Wv, Wqh, Wql, Wkh, Wkl, WvT);
  transpose_convert_x<<<dim3(NPT / 256, DIMC / 64, BATCH), 256, 0, stream>>>(x, xt, xb);
  gram_split<<<640, 256, 0, stream>>>(xb, Gp);
  gram_reduce_mirror<<<BATCH * 36, 256, 0, stream>>>(Gp, Gh, Gl);
  // H = Wq . G  (G symmetric -> NT), split output
  gemm3_nt<true><<<dim3(4, 8, BATCH), 256, 0, stream>>>(
      Wqh, Wql, Gh, Gl, (float*)nullptr, Hh, Hl, DIMC, 0L, s2, s2, 1.0f);
  // S = (1/sqrt(512)) H . Wk^T
  gemm3_nt<false><<<dim3(4, 8, BATCH), 256, 0, stream>>>(
      Hh, Hl, Wkh, Wkl, S, (__bf16*)nullptr, (__bf16*)nullptr,
      DIMC, s2, 0L, s2, 0.044194173824159216f);
  softmax_rows<<<BATCH * DIMC / 4, 256, 0, stream>>>(S, P);
  // M = P . Wv^T
  gemm_nt64x128<<<dim3(4, 8, BATCH), 256, 0, stream>>>(
      P, WvT, Mm, DIMC, s2, 0L, s2);
  // out = M . x (via xt)
  gemm_final<<<2048, 256, 0, stream>>>(Mm, xt, out);
}

// Round 2
// 394.319 us; speedup vs baseline: 1.0570x; 1.0472x over previous
//
#include <hip/hip_runtime.h>
#include <hip/hip_bf16.h>
#include <math.h>

#define DIMC 512
#define NPT  4096
#define BATCH 16
#define KSPLIT 4

typedef __bf16 bf16x4 __attribute__((ext_vector_type(4)));
typedef __bf16 bf16x8 __attribute__((ext_vector_type(8)));
typedef float  f32x4  __attribute__((ext_vector_type(4)));

typedef const __attribute__((address_space(1))) unsigned int guint;
typedef __attribute__((address_space(3))) unsigned int luint;

__device__ inline void gl_lds16(const void* g, void* l) {
  __builtin_amdgcn_global_load_lds((guint*)g, (luint*)l, 16, 0, 0);
}

// ---------------------------------------------------------------------------
// Gram, upper-triangle 128-tiles only, split-K x4, XCD-swizzled 1D grid.
// ---------------------------------------------------------------------------
__global__ __launch_bounds__(256, 4) void gram_split(
    const __bf16* __restrict__ xb, float* __restrict__ Gp)
{
  static const int TI[10] = {0,0,0,0,1,1,1,2,2,3};
  static const int TJ[10] = {0,1,2,3,1,2,3,2,3,3};
  const int id = blockIdx.x;              // 640 = 8 XCD * 8 pair-groups * 10 tiles
  const int xcd = id & 7, slot = id >> 3;
  const int g = slot / 10, t = slot % 10;
  const int pair = xcd + 8 * g;
  const int b = pair >> 2, s = pair & 3;
  const int m0 = TI[t] * 128, n0 = TJ[t] * 128;

  const __bf16* A = xb + (long)b * DIMC * NPT;
  float* C = Gp + (long)pair * DIMC * DIMC;

  __shared__ alignas(16) __bf16 As[128 * 32];
  __shared__ alignas(16) __bf16 Bs[128 * 32];

  const int tid  = threadIdx.x;
  const int wave = tid >> 6, lane = tid & 63;
  const int wr = wave >> 1, wc = wave & 1;
  const int q = lane >> 4, p = lane & 15;
  const int r4 = lane >> 2;
  const int koff = (lane & 3) * 8;

  f32x4 acc[4][4];
#pragma unroll
  for (int i = 0; i < 4; ++i)
#pragma unroll
    for (int j = 0; j < 4; ++j) acc[i][j] = (f32x4){0.f, 0.f, 0.f, 0.f};

  const __bf16* gA = A + (long)m0 * NPT;
  const __bf16* gB = A + (long)n0 * NPT;
  const int kbeg = s * (NPT / KSPLIT), kend = kbeg + NPT / KSPLIT;

  for (int k0 = kbeg; k0 < kend; k0 += 32) {
    __syncthreads();
#pragma unroll
    for (int h = 0; h < 2; ++h) {
      const int chunk = wave + h * 4;
      gl_lds16(gA + (long)(chunk * 16 + r4) * NPT + k0 + koff, &As[chunk * 512]);
      gl_lds16(gB + (long)(chunk * 16 + r4) * NPT + k0 + koff, &Bs[chunk * 512]);
    }
    __syncthreads();

    bf16x8 af[4], bfv[4];
#pragma unroll
    for (int i = 0; i < 4; ++i)
      af[i] = ((const bf16x8*)As)[(wr * 64 + i * 16 + p) * 4 + q];
#pragma unroll
    for (int j = 0; j < 4; ++j)
      bfv[j] = ((const bf16x8*)Bs)[(wc * 64 + j * 16 + p) * 4 + q];
#pragma unroll
    for (int i = 0; i < 4; ++i)
#pragma unroll
      for (int j = 0; j < 4; ++j)
        acc[i][j] = __builtin_amdgcn_mfma_f32_16x16x32_bf16(af[i], bfv[j], acc[i][j], 0, 0, 0);
  }

#pragma unroll
  for (int i = 0; i < 4; ++i) {
    const int row = m0 + wr * 64 + i * 16 + q * 4;
#pragma unroll
    for (int j = 0; j < 4; ++j) {
      const int col = n0 + wc * 64 + j * 16 + p;
#pragma unroll
      for (int r = 0; r < 4; ++r)
        C[(long)(row + r) * DIMC + col] = acc[i][j][r];
    }
  }
}

// ---------------------------------------------------------------------------
// Reduce split-K partials of upper 64-tiles, emit Gh/Gl hi/lo, mirror lower.
// ---------------------------------------------------------------------------
__global__ __launch_bounds__(256) void gram_reduce_mirror(
    const float* __restrict__ Gp, __bf16* __restrict__ Gh, __bf16* __restrict__ Gl)
{
  const int bid = blockIdx.x;
  const int b = bid / 36;
  int rem = bid % 36, I = 0;
  while (rem >= 8 - I) { rem -= 8 - I; ++I; }
  const int J = I + rem;

  __shared__ float T[64][65];
  const int tid = threadIdx.x;
  const int r = tid >> 2, c0 = (tid & 3) * 16;

  float v[16];
#pragma unroll
  for (int e = 0; e < 16; ++e) v[e] = 0.f;
#pragma unroll
  for (int s = 0; s < KSPLIT; ++s) {
    const float* src = Gp + (long)(b * KSPLIT + s) * DIMC * DIMC
                          + (long)(I * 64 + r) * DIMC + J * 64 + c0;
#pragma unroll
    for (int q = 0; q < 4; ++q) {
      float4 t4 = ((const float4*)src)[q];
      v[q * 4 + 0] += t4.x; v[q * 4 + 1] += t4.y;
      v[q * 4 + 2] += t4.z; v[q * 4 + 3] += t4.w;
    }
  }

  const long gbase = (long)b * DIMC * DIMC;
#pragma unroll
  for (int q = 0; q < 4; ++q) {
    bf16x4 h, l;
#pragma unroll
    for (int e = 0; e < 4; ++e) {
      float f = v[q * 4 + e];
      __bf16 hh = (__bf16)f;
      h[e] = hh; l[e] = (__bf16)(f - (float)hh);
    }
    const long o = gbase + (long)(I * 64 + r) * DIMC + J * 64 + c0 + q * 4;
    *(bf16x4*)(Gh + o) = h;
    *(bf16x4*)(Gl + o) = l;
  }
#pragma unroll
  for (int e = 0; e < 16; ++e) T[r][c0 + e] = v[e];
  __syncthreads();
  if (I != J) {
#pragma unroll
    for (int q = 0; q < 4; ++q) {
      bf16x4 h, l;
#pragma unroll
      for (int e = 0; e < 4; ++e) {
        float f = T[c0 + q * 4 + e][r];
        __bf16 hh = (__bf16)f;
        h[e] = hh; l[e] = (__bf16)(f - (float)hh);
      }
      const long o = gbase + (long)(J * 64 + r) * DIMC + I * 64 + c0 + q * 4;
      *(bf16x4*)(Gh + o) = h;
      *(bf16x4*)(Gl + o) = l;
    }
  }
}

// ---------------------------------------------------------------------------
// 3-term hi/lo NT GEMM, 64M x 128N tile, BK=32, 4 waves (2x2, each 32x64).
// ---------------------------------------------------------------------------
template <bool SPLIT_OUT>
__global__ __launch_bounds__(256, 4) void gemm3_nt(
    const __bf16* __restrict__ Ah, const __bf16* __restrict__ Al,
    const __bf16* __restrict__ Bh, const __bf16* __restrict__ Bl,
    float* __restrict__ Cf, __bf16* __restrict__ Ch, __bf16* __restrict__ Cl,
    int K, long sA, long sB, long sC, float alpha)
{
  const int b = blockIdx.z;
  Ah += (long)b * sA;  Al += (long)b * sA;
  Bh += (long)b * sB;  Bl += (long)b * sB;
  const int m0 = blockIdx.y * 64, n0 = blockIdx.x * 128;

  __shared__ alignas(16) __bf16 sAh[64 * 32],  sAl[64 * 32];
  __shared__ alignas(16) __bf16 sBh[128 * 32], sBl[128 * 32];

  const int tid  = threadIdx.x;
  const int wave = tid >> 6, lane = tid & 63;
  const int wr = wave >> 1, wc = wave & 1;
  const int q = lane >> 4, p = lane & 15;
  const int r4 = lane >> 2;
  const int koff = (lane & 3) * 8;

  f32x4 acc[2][4];
#pragma unroll
  for (int i = 0; i < 2; ++i)
#pragma unroll
    for (int j = 0; j < 4; ++j) acc[i][j] = (f32x4){0.f, 0.f, 0.f, 0.f};

  const long arow = (long)(m0 + wave * 16 + r4) * K + koff;

  for (int k0 = 0; k0 < K; k0 += 32) {
    __syncthreads();
    gl_lds16(Ah + arow + k0, &sAh[wave * 512]);
    gl_lds16(Al + arow + k0, &sAl[wave * 512]);
#pragma unroll
    for (int h = 0; h < 2; ++h) {
      const int chunk = wave + h * 4;
      const long brow = (long)(n0 + chunk * 16 + r4) * K + koff + k0;
      gl_lds16(Bh + brow, &sBh[chunk * 512]);
      gl_lds16(Bl + brow, &sBl[chunk * 512]);
    }
    __syncthreads();

    bf16x8 fah[2], fal[2], fbh[4], fbl[4];
#pragma unroll
    for (int i = 0; i < 2; ++i) {
      const int idx = (wr * 32 + i * 16 + p) * 4 + q;
      fah[i] = ((const bf16x8*)sAh)[idx];
      fal[i] = ((const bf16x8*)sAl)[idx];
    }
#pragma unroll
    for (int j = 0; j < 4; ++j) {
      const int idx = (wc * 64 + j * 16 + p) * 4 + q;
      fbh[j] = ((const bf16x8*)sBh)[idx];
      fbl[j] = ((const bf16x8*)sBl)[idx];
    }
#pragma unroll
    for (int i = 0; i < 2; ++i)
#pragma unroll
      for (int j = 0; j < 4; ++j) {
        acc[i][j] = __builtin_amdgcn_mfma_f32_16x16x32_bf16(fah[i], fbh[j], acc[i][j], 0, 0, 0);
        acc[i][j] = __builtin_amdgcn_mfma_f32_16x16x32_bf16(fah[i], fbl[j], acc[i][j], 0, 0, 0);
        acc[i][j] = __builtin_amdgcn_mfma_f32_16x16x32_bf16(fal[i], fbh[j], acc[i][j], 0, 0, 0);
      }
  }

#pragma unroll
  for (int i = 0; i < 2; ++i) {
    const int row = m0 + wr * 32 + i * 16 + q * 4;
#pragma unroll
    for (int j = 0; j < 4; ++j) {
      const int col = n0 + wc * 64 + j * 16 + p;
#pragma unroll
      for (int r = 0; r < 4; ++r) {
        const float f = acc[i][j][r] * alpha;
        const long o = (long)b * sC + (long)(row + r) * DIMC + col;
        if (SPLIT_OUT) {
          __bf16 hh = (__bf16)f;
          Ch[o] = hh;
          Cl[o] = (__bf16)(f - (float)hh);
        } else {
          Cf[o] = f;
        }
      }
    }
  }
}

// ---------------------------------------------------------------------------
// Single-term NT GEMM bf16, 64M x 128N tile (M = P . Wv^T). 3 gl_lds + 8 MFMA.
// ---------------------------------------------------------------------------
__global__ __launch_bounds__(256, 4) void gemm_nt64x128(
    const __bf16* __restrict__ A, const __bf16* __restrict__ B,
    __bf16* __restrict__ C, int K, long sA, long sB, long sC)
{
  const int b = blockIdx.z;
  A += (long)b * sA;  B += (long)b * sB;  C += (long)b * sC;
  const int m0 = blockIdx.y * 64, n0 = blockIdx.x * 128;

  __shared__ alignas(16) __bf16 As[64 * 32];
  __shared__ alignas(16) __bf16 Bs[128 * 32];

  const int tid  = threadIdx.x;
  const int wave = tid >> 6, lane = tid & 63;
  const int wr = wave >> 1, wc = wave & 1;
  const int q = lane >> 4, p = lane & 15;
  const int r4 = lane >> 2;
  const int koff = (lane & 3) * 8;

  f32x4 acc[2][4];
#pragma unroll
  for (int i = 0; i < 2; ++i)
#pragma unroll
    for (int j = 0; j < 4; ++j) acc[i][j] = (f32x4){0.f, 0.f, 0.f, 0.f};

  const long arow = (long)(m0 + wave * 16 + r4) * K + koff;

  for (int k0 = 0; k0 < K; k0 += 32) {
    __syncthreads();
    gl_lds16(A + arow + k0, &As[wave * 512]);
#pragma unroll
    for (int h = 0; h < 2; ++h) {
      const int chunk = wave + h * 4;
      gl_lds16(B + (long)(n0 + chunk * 16 + r4) * K + koff + k0, &Bs[chunk * 512]);
    }
    __syncthreads();

    bf16x8 af[2], bfv[4];
#pragma unroll
    for (int i = 0; i < 2; ++i)
      af[i] = ((const bf16x8*)As)[(wr * 32 + i * 16 + p) * 4 + q];
#pragma unroll
    for (int j = 0; j < 4; ++j)
      bfv[j] = ((const bf16x8*)Bs)[(wc * 64 + j * 16 + p) * 4 + q];
#pragma unroll
    for (int i = 0; i < 2; ++i)
#pragma unroll
      for (int j = 0; j < 4; ++j)
        acc[i][j] = __builtin_amdgcn_mfma_f32_16x16x32_bf16(af[i], bfv[j], acc[i][j], 0, 0, 0);
  }

#pragma unroll
  for (int i = 0; i < 2; ++i) {
    const int row = m0 + wr * 32 + i * 16 + q * 4;
#pragma unroll
    for (int j = 0; j < 4; ++j) {
      const int col = n0 + wc * 64 + j * 16 + p;
#pragma unroll
      for (int r = 0; r < 4; ++r)
        C[(long)(row + r) * DIMC + col] = (__bf16)acc[i][j][r];
    }
  }
}

// ---------------------------------------------------------------------------
// Final GEMM (NN, direct from xb): out_b[d,n] = sum_c Mm_b[d,c] xb_b[c,n].
// A staged via gl_lds16 (rows of Mm). B staged via registers: each thread
// loads 4 c-rows x 4 n (dwordx2, coalesced 256B/row), packs {c,c+1} bf16
// pairs into dwords (2 bit-ops each), ds_write_b64 into Bs[n][c] with an
// 18-dword row stride (both staging writes and b64 fragment reads sit at the
// 512B/wave LDS bandwidth floor; 16B-aligned b128 is impossible at stride 18,
// so fragments assemble from 2x ds_read_b64). 128x128 tile, XCD swizzle.
// ---------------------------------------------------------------------------
__global__ __launch_bounds__(256, 2) void gemm_final(
    const __bf16* __restrict__ Mm, const __bf16* __restrict__ xb,
    float* __restrict__ out)
{
  const int id = blockIdx.x;
  const int xcd = id & 7, slot = id >> 3;
  const int g = slot >> 7, tile = slot & 127;
  const int b = xcd + 8 * g;
  const int m0 = (tile >> 5) * 128, n0 = (tile & 31) * 128;

  const __bf16* A = Mm + (long)b * DIMC * DIMC;
  const __bf16* B = xb + (long)b * DIMC * NPT;
  float* C = out + (long)b * DIMC * NPT;
  const int K = DIMC;

  __shared__ alignas(16) __bf16 As[128 * 32];
  __shared__ alignas(16) unsigned int Bs[128 * 18];   // [n][c-dword], stride 18

  const int tid  = threadIdx.x;
  const int wave = tid >> 6, lane = tid & 63;
  const int wr = wave >> 1, wc = wave & 1;
  const int q = lane >> 4, p = lane & 15;
  const int r4 = lane >> 2;
  const int koff = (lane & 3) * 8;

  // B staging map: ng (low 5 bits) keeps global loads coalesced.
  const int ng = tid & 31;    // n quad: n_local = ng*4 .. +3
  const int cq = tid >> 5;    // c quad: c_local = cq*4 .. +3

  f32x4 acc[4][4];
#pragma unroll
  for (int i = 0; i < 4; ++i)
#pragma unroll
    for (int j = 0; j < 4; ++j) acc[i][j] = (f32x4){0.f, 0.f, 0.f, 0.f};

  const __bf16* gA = A + (long)m0 * K;

  for (int k0 = 0; k0 < K; k0 += 32) {
    __syncthreads();
#pragma unroll
    for (int h = 0; h < 2; ++h) {
      const int chunk = wave + h * 4;
      gl_lds16(gA + (long)(chunk * 16 + r4) * K + k0 + koff, &As[chunk * 512]);
    }
    // B tile: 32 c-rows x 128 n from xb (n contiguous). 4 rows x 4 n/thread.
    uint2 rd[4];
#pragma unroll
    for (int r = 0; r < 4; ++r)
      rd[r] = *(const uint2*)(B + (long)(k0 + cq * 4 + r) * NPT + n0 + ng * 4);
    // Pack per-n {c,c+1} bf16 pairs and write transposed into Bs.
#pragma unroll
    for (int nn = 0; nn < 4; ++nn) {
      const unsigned int s0 = (nn < 2) ? rd[0].x : rd[0].y;
      const unsigned int s1 = (nn < 2) ? rd[1].x : rd[1].y;
      const unsigned int s2 = (nn < 2) ? rd[2].x : rd[2].y;
      const unsigned int s3 = (nn < 2) ? rd[3].x : rd[3].y;
      unsigned int o01, o23;
      if (nn & 1) {
        o01 = (s0 >> 16) | (s1 & 0xffff0000u);
        o23 = (s2 >> 16) | (s3 & 0xffff0000u);
      } else {
        o01 = (s0 & 0xffffu) | (s1 << 16);
        o23 = (s2 & 0xffffu) | (s3 << 16);
      }
      uint2 o; o.x = o01; o.y = o23;
      *(uint2*)&Bs[(ng * 4 + nn) * 18 + cq * 2] = o;   // ds_write_b64, 8B aligned
    }
    __syncthreads();

    bf16x8 af[4], bfv[4];
#pragma unroll
    for (int i = 0; i < 4; ++i)
      af[i] = ((const bf16x8*)As)[(wr * 64 + i * 16 + p) * 4 + q];
#pragma unroll
    for (int j = 0; j < 4; ++j) {
      const unsigned int* bp = &Bs[(wc * 64 + j * 16 + p) * 18 + q * 4];
      const uint2 lo = *(const uint2*)bp;
      const uint2 hi = *(const uint2*)(bp + 2);
      union { uint4 u; bf16x8 v; } cvt;
      cvt.u.x = lo.x; cvt.u.y = lo.y; cvt.u.z = hi.x; cvt.u.w = hi.y;
      bfv[j] = cvt.v;
    }
#pragma unroll
    for (int i = 0; i < 4; ++i)
#pragma unroll
      for (int j = 0; j < 4; ++j)
        acc[i][j] = __builtin_amdgcn_mfma_f32_16x16x32_bf16(af[i], bfv[j], acc[i][j], 0, 0, 0);
  }

#pragma unroll
  for (int i = 0; i < 4; ++i) {
    const int row = m0 + wr * 64 + i * 16 + q * 4;
#pragma unroll
    for (int j = 0; j < 4; ++j) {
      const int col = n0 + wc * 64 + j * 16 + p;
#pragma unroll
      for (int r = 0; r < 4; ++r)
        C[(long)(row + r) * NPT + col] = acc[i][j][r];
    }
  }
}

// ---------------------------------------------------------------------------
// Pure streaming convert: x fp32 [B,512,4096] -> xb bf16 same layout.
// No LDS, no barrier, full occupancy; 2x 16B loads + 1x 16B store per step.
// ---------------------------------------------------------------------------
__global__ __launch_bounds__(256) void convert_x(
    const float* __restrict__ x, __bf16* __restrict__ xb)
{
  const long total8 = (long)BATCH * DIMC * NPT / 8;
  const long stride = (long)gridDim.x * 256;
  for (long i = blockIdx.x * 256 + threadIdx.x; i < total8; i += stride) {
    const f32x4 a = ((const f32x4*)x)[2 * i];
    const f32x4 b = ((const f32x4*)x)[2 * i + 1];
    bf16x8 o;
    o[0] = (__bf16)a[0]; o[1] = (__bf16)a[1];
    o[2] = (__bf16)a[2]; o[3] = (__bf16)a[3];
    o[4] = (__bf16)b[0]; o[5] = (__bf16)b[1];
    o[6] = (__bf16)b[2]; o[7] = (__bf16)b[3];
    ((bf16x8*)xb)[i] = o;
  }
}

// ---------------------------------------------------------------------------
// Row softmax over 512 cols, fp32 in -> bf16 out. One wave per row.
// ---------------------------------------------------------------------------
__global__ __launch_bounds__(256) void softmax_rows(
    const float* __restrict__ S, __bf16* __restrict__ P)
{
  const int row = blockIdx.x * 4 + (threadIdx.x >> 6);
  const int lane = threadIdx.x & 63;
  const float4* s4 = (const float4*)(S + (long)row * DIMC);
  float4 a = s4[lane * 2], b = s4[lane * 2 + 1];
  float v[8] = {a.x, a.y, a.z, a.w, b.x, b.y, b.z, b.w};
  float m = v[0];
#pragma unroll
  for (int i = 1; i < 8; ++i) m = fmaxf(m, v[i]);
#pragma unroll
  for (int off = 32; off > 0; off >>= 1) m = fmaxf(m, __shfl_xor(m, off));
  float e[8], sum = 0.f;
#pragma unroll
  for (int i = 0; i < 8; ++i) { e[i] = expf(v[i] - m); sum += e[i]; }
#pragma unroll
  for (int off = 32; off > 0; off >>= 1) sum += __shfl_xor(sum, off);
  const float inv = 1.0f / sum;
  bf16x8 o;
#pragma unroll
  for (int i = 0; i < 8; ++i) o[i] = (__bf16)(e[i] * inv);
  ((bf16x8*)(P + (long)row * DIMC))[lane] = o;
}

// ---------------------------------------------------------------------------
// Split Wq, Wk into bf16 hi/lo; WvT[c,e] = bf16(Wv[e,c]).
// ---------------------------------------------------------------------------
__global__ __launch_bounds__(256) void make_w(
    const float* __restrict__ Wq, const float* __restrict__ Wk,
    const float* __restrict__ Wv,
    __bf16* __restrict__ Wqh, __bf16* __restrict__ Wql,
    __bf16* __restrict__ Wkh, __bf16* __restrict__ Wkl,
    __bf16* __restrict__ WvT)
{
  const int i = blockIdx.x * 256 + threadIdx.x;
  float q = Wq[i];
  __bf16 qh = (__bf16)q; Wqh[i] = qh; Wql[i] = (__bf16)(q - (float)qh);
  float k = Wk[i];
  __bf16 kh = (__bf16)k; Wkh[i] = kh; Wkl[i] = (__bf16)(k - (float)kh);
  const int e = i >> 9, c = i & 511;
  WvT[(long)c * DIMC + e] = (__bf16)Wv[i];
}

extern "C" void kernel_launch(void* const* d_in, const int* in_sizes, int n_in,
                              void* d_out, int out_size, void* d_ws, size_t ws_size,
                              hipStream_t stream)
{
  const float* x  = (const float*)d_in[0];
  const float* Wq = (const float*)d_in[1];
  const float* Wk = (const float*)d_in[2];
  const float* Wv = (const float*)d_in[3];
  float* out = (float*)d_out;

  char* ws = (char*)d_ws;
  size_t off = 0;
  auto alloc = [&](size_t bytes) -> void* {
    void* p = ws + off;
    off += (bytes + 255) & ~(size_t)255;
    return p;
  };
  const long s2 = (long)DIMC * DIMC;

  __bf16* xb  = (__bf16*)alloc((size_t)BATCH * DIMC * NPT * 2);
  float*  Gp  = (float*) alloc((size_t)KSPLIT * BATCH * s2 * 4);
  __bf16* Gh  = (__bf16*)alloc((size_t)BATCH * s2 * 2);
  __bf16* Gl  = (__bf16*)alloc((size_t)BATCH * s2 * 2);
  __bf16* Hh  = (__bf16*)alloc((size_t)BATCH * s2 * 2);
  __bf16* Hl  = (__bf16*)alloc((size_t)BATCH * s2 * 2);
  __bf16* Wqh = (__bf16*)alloc((size_t)s2 * 2);
  __bf16* Wql = (__bf16*)alloc((size_t)s2 * 2);
  __bf16* Wkh = (__bf16*)alloc((size_t)s2 * 2);
  __bf16* Wkl = (__bf16*)alloc((size_t)s2 * 2);
  __bf16* WvT = (__bf16*)alloc((size_t)s2 * 2);
  float*  S  = (float*)Gp;    // alias: Gp dead after reduce
  __bf16* P  = Gl;            // alias: Gl dead after H-GEMM
  __bf16* Mm = Gh;            // alias: Gh dead after H-GEMM

  make_w<<<DIMC * DIMC / 256, 256, 0, stream>>>(Wq, Wk, Wv, Wqh, Wql, Wkh, Wkl, WvT);
  convert_x<<<2048, 256, 0, stream>>>(x, xb);
  gram_split<<<640, 256, 0, stream>>>(xb, Gp);
  gram_reduce_mirror<<<BATCH * 36, 256, 0, stream>>>(Gp, Gh, Gl);
  // H = Wq . G  (G symmetric -> NT), split output
  gemm3_nt<true><<<dim3(4, 8, BATCH), 256, 0, stream>>>(
      Wqh, Wql, Gh, Gl, (float*)nullptr, Hh, Hl, DIMC, 0L, s2, s2, 1.0f);
  // S = (1/sqrt(512)) H . Wk^T
  gemm3_nt<false><<<dim3(4, 8, BATCH), 256, 0, stream>>>(
      Hh, Hl, Wkh, Wkl, S, (__bf16*)nullptr, (__bf16*)nullptr,
      DIMC, s2, 0L, s2, 0.044194173824159216f);
  softmax_rows<<<BATCH * DIMC / 4, 256, 0, stream>>>(S, P);
  // M = P . Wv^T
  gemm_nt64x128<<<dim3(4, 8, BATCH), 256, 0, stream>>>(
      P, WvT, Mm, DIMC, s2, 0L, s2);
  // out = M . xb (NN, in-kernel B transpose)
  gemm_final<<<2048, 256, 0, stream>>>(Mm, xb, out);
}